// Round 3
// baseline (2466.338 us; speedup 1.0000x reference)
//
#include <hip/hip_runtime.h>
#include <hip/hip_fp16.h>
#include <hip/hip_cooperative_groups.h>
#include <math.h>

namespace cg = cooperative_groups;

#define N_NODES 50000
#define N_EDGES 800000
#define IN_C 96
#define HID_C 64
#define OUT_C 40
#define ALPHA 0.2f
#define NEG_SLOPE 0.01f
#define QCAP 131072
#define NBLK 196   // cdiv(N_NODES,256)
#define EBLK 782   // cdiv(N_EDGES,1024)
#define MTILES 3125  // N_NODES/16
#define SMEM_BYTES 13312  // 64*52*4 (lin0 weight stage, the largest user)

typedef _Float16 f16x8 __attribute__((ext_vector_type(8)));
typedef float f32x4 __attribute__((ext_vector_type(4)));

struct GP {
    const float* x; const void* ei;
    const float* W0; const float* b0; const float* W4; const float* b4;
    float* out;
    int* flag; int* deg; int* rowptr; int* cursor; int* part;
    int* bcnt; int* bbase; int* tot; int* qtail; int* perm;
    float* dinv; int* csrc; int2* queue;
    __half* bufA; __half* bufB; __half* bufC;
};

__device__ __forceinline__ int edge_at(const void* ei, int is64, long long pos) {
    return is64 ? (int)((const long long*)ei)[pos] : ((const int*)ei)[pos];
}

__device__ __forceinline__ void add8(float* acc, float4 v) {
    const __half2* hp = (const __half2*)&v;
    #pragma unroll
    for (int j = 0; j < 4; ++j) {
        float2 f = __half22float2(hp[j]);
        acc[2 * j] += f.x;
        acc[2 * j + 1] += f.y;
    }
}

__device__ __forceinline__ void unpack8(float* acc, float4 r) {
    const __half2* hp = (const __half2*)&r;
    #pragma unroll
    for (int j = 0; j < 4; ++j) {
        float2 f = __half22float2(hp[j]);
        acc[2 * j] = f.x;
        acc[2 * j + 1] = f.y;
    }
}

// 4-deep gather pipeline with next-batch index prefetch; pitch = 8 float4/row.
__device__ __forceinline__ void gather_rows(const float4* __restrict__ in4, int lanecol,
        const int* __restrict__ csrc, int r0, int r1, float* acc) {
    int i = r0;
    int s4[4];
    if (i + 3 < r1) { s4[0]=csrc[i]; s4[1]=csrc[i+1]; s4[2]=csrc[i+2]; s4[3]=csrc[i+3]; }
    for (; i + 7 < r1; i += 4) {
        float4 v0 = in4[(size_t)s4[0] * 8 + lanecol];
        float4 v1 = in4[(size_t)s4[1] * 8 + lanecol];
        float4 v2 = in4[(size_t)s4[2] * 8 + lanecol];
        float4 v3 = in4[(size_t)s4[3] * 8 + lanecol];
        s4[0]=csrc[i+4]; s4[1]=csrc[i+5]; s4[2]=csrc[i+6]; s4[3]=csrc[i+7];
        add8(acc, v0); add8(acc, v1); add8(acc, v2); add8(acc, v3);
    }
    if (i + 3 < r1) {
        float4 v0 = in4[(size_t)s4[0] * 8 + lanecol];
        float4 v1 = in4[(size_t)s4[1] * 8 + lanecol];
        float4 v2 = in4[(size_t)s4[2] * 8 + lanecol];
        float4 v3 = in4[(size_t)s4[3] * 8 + lanecol];
        add8(acc, v0); add8(acc, v1); add8(acc, v2); add8(acc, v3);
        i += 4;
    }
    for (; i < r1; ++i) add8(acc, in4[(size_t)csrc[i] * 8 + lanecol]);
}

// MFMA dense linear phase: out[m,o] = sum_k in[m,k]*W[o,k]; tiles grid-strided.
template <int O, int K, int OP, bool FP32IN, bool SCALE>
__device__ void lin_phase(const void* __restrict__ in_, const float* __restrict__ W,
                          const float* __restrict__ dinv, __half* __restrict__ out,
                          int tile0, int tstride, char* smemraw) {
    constexpr int P2 = 52;
    __half2* wsh = (__half2*)smemraw;
    for (int idx = threadIdx.x; idx < O * (K / 2); idx += 256) {
        int o = idx / (K / 2), kk = idx - o * (K / 2);
        float2 w2 = ((const float2*)W)[o * (K / 2) + kk];
        wsh[o * P2 + kk] = __floats2half2_rn(w2.x, w2.y);
    }
    __syncthreads();
    int lane = threadIdx.x & 63;
    int lm = lane & 15, q = lane >> 4;
    constexpr int NT = (O + 15) / 16;
    const __half* wsp = (const __half*)wsh;
    for (int tile = tile0; tile < MTILES; tile += tstride) {
        long long m0 = (long long)tile * 16;
        f32x4 acc[NT];
        #pragma unroll
        for (int j = 0; j < NT; ++j) acc[j] = (f32x4){0.f, 0.f, 0.f, 0.f};
        #pragma unroll
        for (int k0 = 0; k0 < K; k0 += 32) {
            f16x8 a;
            if (FP32IN) {
                const float* xr = (const float*)in_ + (m0 + lm) * K + k0 + q * 8;
                float4 x0 = ((const float4*)xr)[0];
                float4 x1 = ((const float4*)xr)[1];
                a = (f16x8){(_Float16)x0.x, (_Float16)x0.y, (_Float16)x0.z, (_Float16)x0.w,
                            (_Float16)x1.x, (_Float16)x1.y, (_Float16)x1.z, (_Float16)x1.w};
            } else {
                const __half* xr = (const __half*)in_ + (m0 + lm) * K + k0 + q * 8;
                a = *(const f16x8*)xr;
            }
            #pragma unroll
            for (int j = 0; j < NT; ++j) {
                f16x8 b = *(const f16x8*)(wsp + (16 * j + lm) * (2 * P2) + k0 + q * 8);
                acc[j] = __builtin_amdgcn_mfma_f32_16x16x32_f16(a, b, acc[j], 0, 0, 0);
            }
        }
        #pragma unroll
        for (int r = 0; r < 4; ++r) {
            long long m = m0 + q * 4 + r;
            float sc = SCALE ? dinv[m] : 1.0f;
            #pragma unroll
            for (int j = 0; j < NT; ++j) {
                int col = 16 * j + lm;
                if (col < O) out[m * OP + col] = __float2half(acc[j][r] * sc);
            }
        }
    }
}

// prop64 phase: MODE 0=plain, 1=+dinv*b0, 2=combine, 3=combine+leaky
template <int MODE>
__device__ void prop64_phase(const GP& p, const __half* __restrict__ in,
                             const __half* __restrict__ h0, __half* __restrict__ out, int G) {
    int grp = threadIdx.x >> 3, ci = threadIdx.x & 7;
    const float4* in8 = (const float4*)in;
    for (int g = blockIdx.x * 32 + grp; g < N_NODES; g += G * 32) {
        int node = p.perm[g];
        int r0 = p.rowptr[node], r1 = p.rowptr[node + 1];
        float di = p.dinv[node];
        float acc[8];
        unpack8(acc, in8[(size_t)node * 8 + ci]);
        gather_rows(in8, ci, p.csrc, r0, r1, acc);
        float sc = di * di;
        float v[8];
        #pragma unroll
        for (int j = 0; j < 8; ++j) v[j] = sc * acc[j];
        if (MODE == 1) {
            float4 b0v = ((const float4*)p.b0)[2 * ci];
            float4 b1v = ((const float4*)p.b0)[2 * ci + 1];
            v[0] += di * b0v.x; v[1] += di * b0v.y; v[2] += di * b0v.z; v[3] += di * b0v.w;
            v[4] += di * b1v.x; v[5] += di * b1v.y; v[6] += di * b1v.z; v[7] += di * b1v.w;
        }
        if (MODE >= 2) {
            float h[8];
            unpack8(h, ((const float4*)h0)[(size_t)node * 8 + ci]);
            #pragma unroll
            for (int j = 0; j < 8; ++j) v[j] = (1.0f - ALPHA) * v[j] + ALPHA * h[j];
        }
        if (MODE == 3) {
            #pragma unroll
            for (int j = 0; j < 8; ++j) v[j] = v[j] > 0.0f ? v[j] : NEG_SLOPE * v[j];
        }
        float4 o;
        __half2* op = (__half2*)&o;
        #pragma unroll
        for (int j = 0; j < 4; ++j)
            op[j] = __float22half2_rn(make_float2(v[2 * j], v[2 * j + 1]));
        ((float4*)out)[(size_t)node * 8 + ci] = o;
    }
}

// prop40 phase (padded 128 B rows). SM: + b4 + log_softmax, fp32 out.
template <bool SM>
__device__ void prop40_phase(const GP& p, const __half* __restrict__ in,
                             __half* __restrict__ outh, int G) {
    int grp = threadIdx.x >> 3, ci = threadIdx.x & 7;
    bool act = ci < 5;
    int cc = act ? ci : 0;
    const float4* in4 = (const float4*)in;
    for (int g = blockIdx.x * 32 + grp; g < N_NODES; g += G * 32) {
        int node = p.perm[g];
        int r0 = p.rowptr[node], r1 = p.rowptr[node + 1];
        float di = p.dinv[node];
        float acc[8];
        unpack8(acc, in4[(size_t)node * 8 + cc]);
        gather_rows(in4, cc, p.csrc, r0, r1, acc);
        if (!SM) {
            if (act) {
                float sc = di * di;
                float4 o;
                __half2* op = (__half2*)&o;
                #pragma unroll
                for (int j = 0; j < 4; ++j)
                    op[j] = __float22half2_rn(make_float2(sc * acc[2 * j], sc * acc[2 * j + 1]));
                ((float4*)outh)[(size_t)node * 8 + ci] = o;
            }
        } else {
            float v[8];
            if (act) {
                float4 b0v = ((const float4*)p.b4)[2 * ci];
                float4 b1v = ((const float4*)p.b4)[2 * ci + 1];
                v[0] = di * acc[0] + b0v.x; v[1] = di * acc[1] + b0v.y;
                v[2] = di * acc[2] + b0v.z; v[3] = di * acc[3] + b0v.w;
                v[4] = di * acc[4] + b1v.x; v[5] = di * acc[5] + b1v.y;
                v[6] = di * acc[6] + b1v.z; v[7] = di * acc[7] + b1v.w;
            } else {
                #pragma unroll
                for (int j = 0; j < 8; ++j) v[j] = -INFINITY;
            }
            float m = v[0];
            #pragma unroll
            for (int j = 1; j < 8; ++j) m = fmaxf(m, v[j]);
            #pragma unroll
            for (int off = 4; off >= 1; off >>= 1) m = fmaxf(m, __shfl_xor(m, off));
            float e = 0.0f;
            if (act) {
                #pragma unroll
                for (int j = 0; j < 8; ++j) e += expf(v[j] - m);
            }
            #pragma unroll
            for (int off = 4; off >= 1; off >>= 1) e += __shfl_xor(e, off);
            float ls = m + logf(e);
            if (act) {
                float4 o0 = make_float4(v[0] - ls, v[1] - ls, v[2] - ls, v[3] - ls);
                float4 o1 = make_float4(v[4] - ls, v[5] - ls, v[6] - ls, v[7] - ls);
                ((float4*)p.out)[(size_t)node * 10 + 2 * ci] = o0;
                ((float4*)p.out)[(size_t)node * 10 + 2 * ci + 1] = o1;
            }
        }
    }
}

// =================== THE fused cooperative kernel ===================
__global__ void __launch_bounds__(256, 8) mega_k(GP p, int G) {
    __shared__ __align__(16) char smem[SMEM_BYTES];
    cg::grid_group grid = cg::this_grid();
    const int tid = threadIdx.x, bid = blockIdx.x;
    int* sm = (int*)smem;

    // ---- P0: zero deg + qtail, detect edge dtype ----
    for (int i = bid * 256 + tid; i < N_NODES; i += G * 256) p.deg[i] = 0;
    if (bid == 0) {
        if (tid < 8) p.qtail[tid] = 0;
        if (tid == 0) {
            const unsigned* e = (const unsigned*)p.ei;
            int is64 = 1;
            for (int j = 1; j < 16; j += 2) if (e[j]) is64 = 0;
            *p.flag = is64;
        }
    }
    grid.sync();

    // ---- P1: bucketA (degree histogram + partition queues) ----
    {
        int* cnt = sm; int* qb = sm + 8;
        int f = *p.flag;
        for (int vb = bid; vb < EBLK; vb += G) {
            if (tid < 8) cnt[tid] = 0;
            __syncthreads();
            int e0 = vb * 1024;
            int s[4], d[4], pt[4], r[4];
            #pragma unroll
            for (int k = 0; k < 4; ++k) {
                int e = e0 + tid + k * 256;
                if (e < N_EDGES) {
                    d[k] = edge_at(p.ei, f, (long long)N_EDGES + e);
                    s[k] = edge_at(p.ei, f, e);
                    atomicAdd(&p.deg[d[k]], 1);
                    pt[k] = d[k] / (N_NODES / 8);
                    if (pt[k] > 7) pt[k] = 7;
                    r[k] = atomicAdd(&cnt[pt[k]], 1);
                } else pt[k] = -1;
            }
            __syncthreads();
            if (tid < 8) qb[tid] = atomicAdd(&p.qtail[tid], cnt[tid]);
            __syncthreads();
            #pragma unroll
            for (int k = 0; k < 4; ++k) {
                if (pt[k] >= 0) {
                    int pos = qb[pt[k]] + r[k];
                    if (pos < QCAP) p.queue[(size_t)pt[k] * QCAP + pos] = make_int2(s[k], d[k]);
                }
            }
            __syncthreads();
        }
    }
    grid.sync();

    // ---- P2: scan phase 1 (per-block sums) ----
    for (int vb = bid; vb < NBLK; vb += G) {
        int i = vb * 256 + tid;
        int v = (i < N_NODES) ? p.deg[i] : 0;
        sm[tid] = v;
        __syncthreads();
        for (int off = 1; off < 256; off <<= 1) {
            int u = (tid >= off) ? sm[tid - off] : 0;
            __syncthreads(); sm[tid] += u; __syncthreads();
        }
        if (tid == 255) p.part[vb] = sm[255];
        __syncthreads();
    }
    grid.sync();

    // ---- P3: scan phase 2 (block-sum exclusive scan) ----
    if (bid == 0) {
        int v = (tid < NBLK) ? p.part[tid] : 0;
        sm[tid] = v;
        __syncthreads();
        for (int off = 1; off < 256; off <<= 1) {
            int u = (tid >= off) ? sm[tid - off] : 0;
            __syncthreads(); sm[tid] += u; __syncthreads();
        }
        if (tid < NBLK) p.part[tid] = sm[tid] - v;
        if (tid == 255) p.rowptr[N_NODES] = sm[255];
    }
    grid.sync();

    // ---- P4: scan phase 3 + degree-bucket histogram ----
    {
        int* hh = sm + 256;
        for (int vb = bid; vb < NBLK; vb += G) {
            if (tid < 64) hh[tid] = 0;
            int i = vb * 256 + tid;
            int v = (i < N_NODES) ? p.deg[i] : 0;
            sm[tid] = v;
            __syncthreads();
            for (int off = 1; off < 256; off <<= 1) {
                int u = (tid >= off) ? sm[tid - off] : 0;
                __syncthreads(); sm[tid] += u; __syncthreads();
            }
            if (i < N_NODES) {
                int excl = sm[tid] - v + p.part[vb];
                p.rowptr[i] = excl;
                p.cursor[i] = excl;
                p.dinv[i] = rsqrtf((float)v + 1.0f);
                int dd = v > 63 ? 63 : v;
                atomicAdd(&hh[63 - dd], 1);
            }
            __syncthreads();
            if (tid < 64) p.bcnt[vb * 64 + tid] = hh[tid];
            __syncthreads();
        }
    }
    grid.sync();

    // ---- P5: bscanA (blocks 0..63)  ||  lin0 MFMA (blocks 64..) ----
    if (bid < 64) {
        int b = bid;
        int v = (tid < NBLK) ? p.bcnt[tid * 64 + b] : 0;
        sm[tid] = v;
        __syncthreads();
        for (int off = 1; off < 256; off <<= 1) {
            int u = (tid >= off) ? sm[tid - off] : 0;
            __syncthreads(); sm[tid] += u; __syncthreads();
        }
        if (tid < NBLK) p.bbase[tid * 64 + b] = sm[tid] - v;
        if (tid == 255) p.tot[b] = sm[255];
    } else {
        lin_phase<HID_C, IN_C, HID_C, true, true>(
            p.x, p.W0, p.dinv, p.bufA, (bid - 64) * 4 + (tid >> 6), (G - 64) * 4, smem);
    }
    grid.sync();

    // ---- P6: perm (blocks 0..195)  ||  bucketB scatter (blocks 196..) ----
    if (bid < NBLK) {
        int* hh = sm + 256; int* bs = sm + 256 + 64;
        if (tid < 64) { hh[tid] = 0; bs[tid] = p.tot[tid]; }
        __syncthreads();
        if (tid == 0) {
            int run = 0;
            for (int k = 0; k < 64; ++k) { int v = bs[k]; bs[k] = run; run += v; }
        }
        __syncthreads();
        int i = bid * 256 + tid;
        if (i < N_NODES) {
            int d = p.deg[i]; if (d > 63) d = 63;
            int b = 63 - d;
            int rank = atomicAdd(&hh[b], 1);
            p.perm[bs[b] + p.bbase[bid * 64 + b] + rank] = i;
        }
    } else {
        int vb = bid - NBLK, J = (G - NBLK) >> 3;
        int p8 = vb & 7, j = vb >> 3;
        if (j < J) {
            int n = p.qtail[p8]; if (n > QCAP) n = QCAP;
            const int2* q = p.queue + (size_t)p8 * QCAP;
            for (int i2 = j * 256 + tid; i2 < n; i2 += J * 256) {
                int2 e = q[i2];
                int pos = atomicAdd(&p.cursor[e.y], 1);
                p.csrc[pos] = e.x;
            }
        }
    }
    grid.sync();

    // ---- conv0 hops (G-space) ----
    prop64_phase<0>(p, p.bufA, nullptr, p.bufB, G); grid.sync();
    prop64_phase<1>(p, p.bufB, nullptr, p.bufC, G); grid.sync();  // + dinv*b0 -> Gh0

    // ---- conv1..conv3: leaky(APPNP(h)) in G-space; Gh0 = bufC ----
    #pragma unroll 1
    for (int r = 0; r < 3; ++r) {
        prop64_phase<2>(p, p.bufC, p.bufC, p.bufB, G); grid.sync();
        prop64_phase<3>(p, p.bufB, p.bufC, p.bufC, G); grid.sync();  // in-place safe
    }

    // ---- conv4: lin (padded 128 B rows), 2 hops at 40ch, softmax ----
    lin_phase<OUT_C, HID_C, HID_C, false, false>(
        p.bufC, p.W4, p.dinv, p.bufA, bid * 4 + (tid >> 6), G * 4, smem);
    grid.sync();
    prop40_phase<false>(p, p.bufA, p.bufB, G); grid.sync();
    prop40_phase<true>(p, p.bufB, nullptr, G);
}

// ---------------- launcher ----------------
static inline int cdiv(long long a, long long b) { return (int)((a + b - 1) / b); }
static inline size_t align256(size_t x) { return (x + 255) & ~(size_t)255; }

extern "C" void kernel_launch(void* const* d_in, const int* in_sizes, int n_in,
                              void* d_out, int out_size, void* d_ws, size_t ws_size,
                              hipStream_t stream) {
    const int N = N_NODES, E = N_EDGES;
    char* ws = (char*)d_ws;
    GP p;
    p.x  = (const float*)d_in[0];
    p.ei = d_in[1];
    p.W0 = (const float*)d_in[2];
    p.b0 = (const float*)d_in[3];
    p.W4 = (const float*)d_in[4];
    p.b4 = (const float*)d_in[5];
    p.out = (float*)d_out;

    p.flag   = (int*)ws;     ws += 256;
    p.deg    = (int*)ws;     ws += align256((size_t)N * 4);
    p.rowptr = (int*)ws;     ws += align256((size_t)(N + 1) * 4);
    p.cursor = (int*)ws;     ws += align256((size_t)N * 4);
    p.part   = (int*)ws;     ws += align256(256 * 4);
    p.bcnt   = (int*)ws;     ws += align256((size_t)NBLK * 64 * 4);
    p.bbase  = (int*)ws;     ws += align256((size_t)NBLK * 64 * 4);
    p.tot    = (int*)ws;     ws += align256(64 * 4);
    p.qtail  = (int*)ws;     ws += align256(8 * 4);
    p.perm   = (int*)ws;     ws += align256((size_t)N * 4);
    p.dinv   = (float*)ws;   ws += align256((size_t)N * 4);
    p.csrc   = (int*)ws;     ws += align256((size_t)E * 4);
    p.queue  = (int2*)ws;    ws += align256((size_t)8 * QCAP * 8);
    p.bufA   = (__half*)ws;  ws += align256((size_t)N * HID_C * 2);
    p.bufB   = (__half*)ws;  ws += align256((size_t)N * HID_C * 2);
    p.bufC   = (__half*)ws;  ws += align256((size_t)N * HID_C * 2);

    // grid: one block per 32 node-groups, capped at guaranteed co-residency
    int occ = 0;
    if (hipOccupancyMaxActiveBlocksPerMultiprocessor(&occ, mega_k, 256, 0) != hipSuccess
        || occ < 1) occ = 6;
    int G = cdiv(N, 32);              // 1563
    int cap = occ * 256;              // 256 CUs on MI355X
    if (G > cap) G = cap;

    void* args[] = { &p, &G };
    hipLaunchCooperativeKernel((void*)mega_k, dim3(G), dim3(256), args, 0, stream);
}

// Round 4
// 821.590 us; speedup vs baseline: 3.0019x; 3.0019x over previous
//
#include <hip/hip_runtime.h>
#include <hip/hip_fp16.h>
#include <hip/hip_cooperative_groups.h>
#include <math.h>

namespace cg = cooperative_groups;

#define N_NODES 50000
#define N_EDGES 800000
#define IN_C 96
#define HID_C 64
#define OUT_C 40
#define ALPHA 0.2f
#define NEG_SLOPE 0.01f
#define QCAP 131072

typedef _Float16 f16x8 __attribute__((ext_vector_type(8)));
typedef float f32x4 __attribute__((ext_vector_type(4)));

struct GP {
    const float* b0;
    int* rowptr; int* perm; float* dinv; int* csrc;
    __half* bufA; __half* bufB; __half* bufC;
};

__device__ __forceinline__ int edge_at(const void* ei, int is64, long long pos) {
    return is64 ? (int)((const long long*)ei)[pos] : ((const int*)ei)[pos];
}

// ---------------- zero deg + qtail + edge dtype detect (fused) ----------------
__global__ void zero_detect_k(int* deg, int n, int* qtail, const unsigned int* ei, int* flag) {
    int i = blockIdx.x * blockDim.x + threadIdx.x;
    if (i < n) deg[i] = 0;
    if (i < 8) qtail[i] = 0;
    if (i == 0) {
        int is64 = 1;
        for (int j = 1; j < 16; j += 2)
            if (ei[j] != 0u) is64 = 0;
        *flag = is64;
    }
}

// ---- phase A: one pass over edges; block-level partition reservation ----
__global__ void bucketA_k(const void* ei, const int* flag, int* __restrict__ deg,
                          int* __restrict__ qtail, int2* __restrict__ queue, int E) {
    __shared__ int cnt[8], qb[8];
    int f = *flag;
    int e0 = blockIdx.x * 1024;
    if (threadIdx.x < 8) cnt[threadIdx.x] = 0;
    __syncthreads();
    int s[4], d[4], p[4], r[4];
    #pragma unroll
    for (int k = 0; k < 4; ++k) {
        int e = e0 + threadIdx.x + k * 256;
        if (e < E) {
            d[k] = edge_at(ei, f, (long long)E + e);
            s[k] = edge_at(ei, f, e);
            atomicAdd(&deg[d[k]], 1);
            p[k] = d[k] / (N_NODES / 8);
            if (p[k] > 7) p[k] = 7;
            r[k] = atomicAdd(&cnt[p[k]], 1);
        } else p[k] = -1;
    }
    __syncthreads();
    if (threadIdx.x < 8) qb[threadIdx.x] = atomicAdd(&qtail[threadIdx.x], cnt[threadIdx.x]);
    __syncthreads();
    #pragma unroll
    for (int k = 0; k < 4; ++k) {
        if (p[k] >= 0) {
            int pos = qb[p[k]] + r[k];
            if (pos < QCAP) queue[(size_t)p[k] * QCAP + pos] = make_int2(s[k], d[k]);
        }
    }
}

// ---- phase B: per-partition streaming scatter into csrc ----
__global__ void bucketB_k(const int* __restrict__ qtail, const int2* __restrict__ queue,
                          int* __restrict__ cursor, int* __restrict__ csrc) {
    int p = blockIdx.x & 7;
    int j = blockIdx.x >> 3;
    int J = gridDim.x >> 3;
    int n = qtail[p]; if (n > QCAP) n = QCAP;
    const int2* q = queue + (size_t)p * QCAP;
    for (int i = j * blockDim.x + threadIdx.x; i < n; i += J * blockDim.x) {
        int2 e = q[i];
        int pos = atomicAdd(&cursor[e.y], 1);
        csrc[pos] = e.x;
    }
}

// ---- parallel 3-phase exclusive scan over deg[n] ----
__global__ void scan_p1_k(const int* __restrict__ deg, int* __restrict__ part, int n) {
    __shared__ int sm[256];
    int t = threadIdx.x, i = blockIdx.x * 256 + t;
    int v = (i < n) ? deg[i] : 0;
    sm[t] = v;
    __syncthreads();
    for (int off = 1; off < 256; off <<= 1) {
        int u = (t >= off) ? sm[t - off] : 0;
        __syncthreads();
        sm[t] += u;
        __syncthreads();
    }
    if (t == 255) part[blockIdx.x] = sm[255];
}

__global__ void scan_p2_k(int* part, int nb, int* rowptr, int n) {
    __shared__ int sm[256];
    int t = threadIdx.x;
    int v = (t < nb) ? part[t] : 0;
    sm[t] = v;
    __syncthreads();
    for (int off = 1; off < 256; off <<= 1) {
        int u = (t >= off) ? sm[t - off] : 0;
        __syncthreads();
        sm[t] += u;
        __syncthreads();
    }
    if (t < nb) part[t] = sm[t] - v;  // exclusive
    if (t == 255) rowptr[n] = sm[255];
}

// scan_p3 + bucket histogram fused
__global__ void scan_p3_k(const int* __restrict__ deg, const int* __restrict__ part,
                          int* __restrict__ rowptr, int* __restrict__ cursor,
                          float* __restrict__ dinv, int* __restrict__ bcnt, int n) {
    __shared__ int sm[256];
    __shared__ int h[64];
    int t = threadIdx.x, i = blockIdx.x * 256 + t;
    if (t < 64) h[t] = 0;
    int v = (i < n) ? deg[i] : 0;
    sm[t] = v;
    __syncthreads();
    for (int off = 1; off < 256; off <<= 1) {
        int u = (t >= off) ? sm[t - off] : 0;
        __syncthreads();
        sm[t] += u;
        __syncthreads();
    }
    if (i < n) {
        int excl = sm[t] - v + part[blockIdx.x];
        rowptr[i] = excl;
        cursor[i] = excl;
        dinv[i] = rsqrtf((float)v + 1.0f);  // +1 self loop
        int dd = v; if (dd > 63) dd = 63;
        atomicAdd(&h[63 - dd], 1);          // bucket = 63-deg (descending)
    }
    __syncthreads();
    if (t < 64) bcnt[blockIdx.x * 64 + t] = h[t];
}

__global__ void bscanA_k(const int* __restrict__ bcnt, int* __restrict__ bbase,
                         int* __restrict__ tot, int nb) {
    __shared__ int sm[256];
    int b = blockIdx.x;
    int t = threadIdx.x;
    int v = (t < nb) ? bcnt[t * 64 + b] : 0;
    sm[t] = v;
    __syncthreads();
    for (int off = 1; off < 256; off <<= 1) {
        int u = (t >= off) ? sm[t - off] : 0;
        __syncthreads();
        sm[t] += u;
        __syncthreads();
    }
    if (t < nb) bbase[t * 64 + b] = sm[t] - v;
    if (t == 255) tot[b] = sm[255];
}

__global__ void perm_k(const int* __restrict__ deg, const int* __restrict__ bbase,
                       const int* __restrict__ tot, int* __restrict__ perm, int n) {
    __shared__ int h[64], bs[64];
    int t = threadIdx.x, i = blockIdx.x * 256 + t;
    if (t < 64) { h[t] = 0; bs[t] = tot[t]; }
    __syncthreads();
    if (t == 0) {
        int run = 0;
        for (int k = 0; k < 64; ++k) { int v = bs[k]; bs[k] = run; run += v; }
    }
    __syncthreads();
    if (i < n) {
        int d = deg[i]; if (d > 63) d = 63;
        int b = 63 - d;
        int rank = atomicAdd(&h[b], 1);
        perm[bs[b] + bbase[blockIdx.x * 64 + b] + rank] = i;
    }
}

// ---------------- shared prop helpers ----------------
__device__ __forceinline__ void add8(float* acc, float4 v) {
    const __half2* hp = (const __half2*)&v;
    #pragma unroll
    for (int j = 0; j < 4; ++j) {
        float2 f = __half22float2(hp[j]);
        acc[2 * j] += f.x;
        acc[2 * j + 1] += f.y;
    }
}

__device__ __forceinline__ void unpack8(float* acc, float4 r) {
    const __half2* hp = (const __half2*)&r;
    #pragma unroll
    for (int j = 0; j < 4; ++j) {
        float2 f = __half22float2(hp[j]);
        acc[2 * j] = f.x;
        acc[2 * j + 1] = f.y;
    }
}

// 8-deep gather pipeline with next-batch index prefetch (R2-proven), pitch 8 f4.
__device__ __forceinline__ void gather8(const float4* __restrict__ in8, int ci,
        const int* __restrict__ csrc, int r0, int r1, float* acc) {
    int i = r0;
    int s[8];
    if (i + 7 < r1) {
        #pragma unroll
        for (int j = 0; j < 8; ++j) s[j] = csrc[i + j];
    }
    for (; i + 15 < r1; i += 8) {
        float4 v[8];
        #pragma unroll
        for (int j = 0; j < 8; ++j) v[j] = in8[(size_t)s[j] * 8 + ci];
        #pragma unroll
        for (int j = 0; j < 8; ++j) s[j] = csrc[i + 8 + j];
        #pragma unroll
        for (int j = 0; j < 8; ++j) add8(acc, v[j]);
    }
    if (i + 7 < r1) {
        float4 v[8];
        #pragma unroll
        for (int j = 0; j < 8; ++j) v[j] = in8[(size_t)s[j] * 8 + ci];
        #pragma unroll
        for (int j = 0; j < 8; ++j) add8(acc, v[j]);
        i += 8;
    }
    for (; i + 3 < r1; i += 4) {
        int s0 = csrc[i], s1 = csrc[i + 1], s2 = csrc[i + 2], s3 = csrc[i + 3];
        float4 v0 = in8[(size_t)s0 * 8 + ci];
        float4 v1 = in8[(size_t)s1 * 8 + ci];
        float4 v2 = in8[(size_t)s2 * 8 + ci];
        float4 v3 = in8[(size_t)s3 * 8 + ci];
        add8(acc, v0); add8(acc, v1); add8(acc, v2); add8(acc, v3);
    }
    for (; i < r1; ++i) add8(acc, in8[(size_t)csrc[i] * 8 + ci]);
}

// prop64 body: MODE 0=plain, 1=+dinv*b0, 2=combine, 3=combine+leaky.
// Grid-stride-safe: out never aliases in/h0 (A/B/C rotation in caller).
template <int MODE>
__device__ void prop64_body(const GP& p, const __half* __restrict__ in,
                            const __half* __restrict__ h0, __half* __restrict__ out, int G) {
    int grp = threadIdx.x >> 3, ci = threadIdx.x & 7;
    const float4* in8 = (const float4*)in;
    for (int g = blockIdx.x * 32 + grp; g < N_NODES; g += G * 32) {
        int node = p.perm[g];
        int r0 = p.rowptr[node], r1 = p.rowptr[node + 1];
        float di = p.dinv[node];
        float acc[8];
        unpack8(acc, in8[(size_t)node * 8 + ci]);
        gather8(in8, ci, p.csrc, r0, r1, acc);
        float sc = di * di;
        float v[8];
        #pragma unroll
        for (int j = 0; j < 8; ++j) v[j] = sc * acc[j];
        if (MODE == 1) {
            float4 b0v = ((const float4*)p.b0)[2 * ci];
            float4 b1v = ((const float4*)p.b0)[2 * ci + 1];
            v[0] += di * b0v.x; v[1] += di * b0v.y; v[2] += di * b0v.z; v[3] += di * b0v.w;
            v[4] += di * b1v.x; v[5] += di * b1v.y; v[6] += di * b1v.z; v[7] += di * b1v.w;
        }
        if (MODE >= 2) {
            float h[8];
            unpack8(h, ((const float4*)h0)[(size_t)node * 8 + ci]);
            #pragma unroll
            for (int j = 0; j < 8; ++j) v[j] = (1.0f - ALPHA) * v[j] + ALPHA * h[j];
        }
        if (MODE == 3) {
            #pragma unroll
            for (int j = 0; j < 8; ++j) v[j] = v[j] > 0.0f ? v[j] : NEG_SLOPE * v[j];
        }
        float4 o;
        __half2* op = (__half2*)&o;
        #pragma unroll
        for (int j = 0; j < 4; ++j)
            op[j] = __float22half2_rn(make_float2(v[2 * j], v[2 * j + 1]));
        ((float4*)out)[(size_t)node * 8 + ci] = o;
    }
}

// ======== cooperative core: the 8 dependent C=64 prop passes, fused ========
// Buffer rotation (no phase writes what it reads; grid-stride safe):
//   A--p0-->B--p1(bias)-->C(Gh0)
//   r0: C->B(comb), B->A(comb+leaky, h0=C)   => h1 = A
//   r1: A->B(comb, h0=A), B->C(comb+leaky, h0=A)  => h2 = C
//   r2: C->B(comb, h0=C), B->A(comb+leaky, h0=C)  => h3 = A
__global__ void __launch_bounds__(256) prop_core_k(GP p, int G) {
    cg::grid_group grid = cg::this_grid();
    prop64_body<0>(p, p.bufA, nullptr, p.bufB, G); grid.sync();
    prop64_body<1>(p, p.bufB, nullptr, p.bufC, G); grid.sync();
    prop64_body<2>(p, p.bufC, p.bufC, p.bufB, G);  grid.sync();
    prop64_body<3>(p, p.bufB, p.bufC, p.bufA, G);  grid.sync();
    prop64_body<2>(p, p.bufA, p.bufA, p.bufB, G);  grid.sync();
    prop64_body<3>(p, p.bufB, p.bufA, p.bufC, G);  grid.sync();
    prop64_body<2>(p, p.bufC, p.bufC, p.bufB, G);  grid.sync();
    prop64_body<3>(p, p.bufB, p.bufC, p.bufA, G);  // h3 -> bufA
}

// ---------------- C=40 prop, padded 128 B rows (R2-proven) ----------------
__global__ void __launch_bounds__(256) prop40_k(
        const int* __restrict__ perm,
        const int* __restrict__ rowptr, const int* __restrict__ csrc,
        const float* __restrict__ dinv,
        const __half* __restrict__ in, __half* __restrict__ out, int N) {
    int g = blockIdx.x * (blockDim.x >> 3) + (threadIdx.x >> 3);
    int ci = threadIdx.x & 7;
    if (g >= N) return;
    int node = perm[g];
    bool act = ci < 5;
    int cc = act ? ci : 0;
    const float4* in4 = (const float4*)in;
    float acc[8];
    unpack8(acc, in4[(size_t)node * 8 + cc]);
    int r0 = rowptr[node], r1 = rowptr[node + 1];
    gather8(in4, cc, csrc, r0, r1, acc);
    if (act) {
        float di = dinv[node];
        float sc = di * di;
        float4 o;
        __half2* op = (__half2*)&o;
        #pragma unroll
        for (int j = 0; j < 4; ++j)
            op[j] = __float22half2_rn(make_float2(sc * acc[2 * j], sc * acc[2 * j + 1]));
        ((float4*)out)[(size_t)node * 8 + ci] = o;
    }
}

// ---------------- final C=40 prop + b4 + log_softmax, fp32 out ----------------
__global__ void __launch_bounds__(256) prop40_softmax_k(
        const int* __restrict__ perm,
        const int* __restrict__ rowptr, const int* __restrict__ csrc,
        const float* __restrict__ dinv,
        const __half* __restrict__ in, const float* __restrict__ bias,
        float* __restrict__ out, int N) {
    int g = blockIdx.x * (blockDim.x >> 3) + (threadIdx.x >> 3);
    int ci = threadIdx.x & 7;
    if (g >= N) return;
    int node = perm[g];
    bool act = ci < 5;
    int cc = act ? ci : 0;
    const float4* in4 = (const float4*)in;
    float acc[8];
    unpack8(acc, in4[(size_t)node * 8 + cc]);
    int r0 = rowptr[node], r1 = rowptr[node + 1];
    gather8(in4, cc, csrc, r0, r1, acc);
    float di = dinv[node];
    float v[8];
    if (act) {
        float4 b0v = ((const float4*)bias)[2 * ci];
        float4 b1v = ((const float4*)bias)[2 * ci + 1];
        v[0] = di * acc[0] + b0v.x; v[1] = di * acc[1] + b0v.y;
        v[2] = di * acc[2] + b0v.z; v[3] = di * acc[3] + b0v.w;
        v[4] = di * acc[4] + b1v.x; v[5] = di * acc[5] + b1v.y;
        v[6] = di * acc[6] + b1v.z; v[7] = di * acc[7] + b1v.w;
    } else {
        #pragma unroll
        for (int j = 0; j < 8; ++j) v[j] = -INFINITY;
    }
    float m = v[0];
    #pragma unroll
    for (int j = 1; j < 8; ++j) m = fmaxf(m, v[j]);
    #pragma unroll
    for (int off = 4; off >= 1; off >>= 1) m = fmaxf(m, __shfl_xor(m, off));
    float e = 0.0f;
    if (act) {
        #pragma unroll
        for (int j = 0; j < 8; ++j) e += expf(v[j] - m);
    }
    #pragma unroll
    for (int off = 4; off >= 1; off >>= 1) e += __shfl_xor(e, off);
    float ls = m + logf(e);
    if (act) {
        float4 o0 = make_float4(v[0] - ls, v[1] - ls, v[2] - ls, v[3] - ls);
        float4 o1 = make_float4(v[4] - ls, v[5] - ls, v[6] - ls, v[7] - ls);
        ((float4*)out)[(size_t)node * 10 + 2 * ci] = o0;
        ((float4*)out)[(size_t)node * 10 + 2 * ci + 1] = o1;
    }
}

// ---------------- MFMA dense linear ----------------
template <int O, int K, int OP, bool FP32IN, bool SCALE>
__global__ void __launch_bounds__(256) mfma_lin_k(const void* __restrict__ in_,
                                                  const float* __restrict__ W,
                                                  const float* __restrict__ dinv,
                                                  __half* __restrict__ out, int Mtiles) {
    constexpr int P2 = 52;
    __shared__ __half2 wsh[O * P2];
    for (int idx = threadIdx.x; idx < O * (K / 2); idx += 256) {
        int o = idx / (K / 2), kk = idx - o * (K / 2);
        float2 w2 = ((const float2*)W)[o * (K / 2) + kk];
        wsh[o * P2 + kk] = __floats2half2_rn(w2.x, w2.y);
    }
    __syncthreads();
    int wave = (blockIdx.x * 256 + threadIdx.x) >> 6;
    if (wave >= Mtiles) return;
    int lane = threadIdx.x & 63;
    int lm = lane & 15, q = lane >> 4;
    long long m0 = (long long)wave * 16;
    constexpr int NT = (O + 15) / 16;
    f32x4 acc[NT];
    #pragma unroll
    for (int j = 0; j < NT; ++j) acc[j] = (f32x4){0.f, 0.f, 0.f, 0.f};
    const __half* wsp = (const __half*)wsh;
    #pragma unroll
    for (int k0 = 0; k0 < K; k0 += 32) {
        f16x8 a;
        if (FP32IN) {
            const float* xr = (const float*)in_ + (m0 + lm) * K + k0 + q * 8;
            float4 x0 = ((const float4*)xr)[0];
            float4 x1 = ((const float4*)xr)[1];
            a = (f16x8){(_Float16)x0.x, (_Float16)x0.y, (_Float16)x0.z, (_Float16)x0.w,
                        (_Float16)x1.x, (_Float16)x1.y, (_Float16)x1.z, (_Float16)x1.w};
        } else {
            const __half* xr = (const __half*)in_ + (m0 + lm) * K + k0 + q * 8;
            a = *(const f16x8*)xr;
        }
        #pragma unroll
        for (int j = 0; j < NT; ++j) {
            f16x8 b = *(const f16x8*)(wsp + (16 * j + lm) * (2 * P2) + k0 + q * 8);
            acc[j] = __builtin_amdgcn_mfma_f32_16x16x32_f16(a, b, acc[j], 0, 0, 0);
        }
    }
    #pragma unroll
    for (int r = 0; r < 4; ++r) {
        long long m = m0 + q * 4 + r;
        float sc = SCALE ? dinv[m] : 1.0f;
        #pragma unroll
        for (int j = 0; j < NT; ++j) {
            int col = 16 * j + lm;
            if (col < O) out[m * OP + col] = __float2half(acc[j][r] * sc);
        }
    }
}

// ---------------- launcher ----------------
static inline int cdiv(long long a, long long b) { return (int)((a + b - 1) / b); }
static inline size_t align256(size_t x) { return (x + 255) & ~(size_t)255; }

extern "C" void kernel_launch(void* const* d_in, const int* in_sizes, int n_in,
                              void* d_out, int out_size, void* d_ws, size_t ws_size,
                              hipStream_t stream) {
    const float* x  = (const float*)d_in[0];
    const void*  ei = d_in[1];
    const float* W0 = (const float*)d_in[2];
    const float* b0 = (const float*)d_in[3];
    const float* W4 = (const float*)d_in[4];
    const float* b4 = (const float*)d_in[5];
    float* out = (float*)d_out;

    const int N = N_NODES, E = N_EDGES;
    const int NB = cdiv(N, 256);  // 196
    char* ws = (char*)d_ws;
    int*    flag   = (int*)ws;     ws += 256;
    int*    deg    = (int*)ws;     ws += align256((size_t)N * 4);
    int*    rowptr = (int*)ws;     ws += align256((size_t)(N + 1) * 4);
    int*    cursor = (int*)ws;     ws += align256((size_t)N * 4);
    int*    part   = (int*)ws;     ws += align256(256 * 4);
    int*    bcnt   = (int*)ws;     ws += align256((size_t)NB * 64 * 4);
    int*    bbase  = (int*)ws;     ws += align256((size_t)NB * 64 * 4);
    int*    tot    = (int*)ws;     ws += align256(64 * 4);
    int*    qtail  = (int*)ws;     ws += align256(8 * 4);
    int*    perm   = (int*)ws;     ws += align256((size_t)N * 4);
    float*  dinv   = (float*)ws;   ws += align256((size_t)N * 4);
    int*    csrc   = (int*)ws;     ws += align256((size_t)E * 4);
    int2*   queue  = (int2*)ws;    ws += align256((size_t)8 * QCAP * 8);
    __half* bufA   = (__half*)ws;  ws += align256((size_t)N * HID_C * 2);
    __half* bufB   = (__half*)ws;  ws += align256((size_t)N * HID_C * 2);
    __half* bufC   = (__half*)ws;  ws += align256((size_t)N * HID_C * 2);

    const int T = 256;
    const int MT = N / 16;             // 3125 MFMA tiles
    const int LB = cdiv(MT, 4);        // mfma_lin blocks (4 waves each)
    const int P40B = cdiv(N, T / 8);   // prop40 blocks (32 groups each)

    GP p;
    p.b0 = b0;
    p.rowptr = rowptr; p.perm = perm; p.dinv = dinv; p.csrc = csrc;
    p.bufA = bufA; p.bufB = bufB; p.bufC = bufC;

    // ---- CSR build (two-phase partition queues) + degree sort ----
    zero_detect_k<<<cdiv(N, T), T, 0, stream>>>(deg, N, qtail, (const unsigned int*)ei, flag);
    bucketA_k<<<cdiv(E, 1024), T, 0, stream>>>(ei, flag, deg, qtail, queue, E);
    scan_p1_k<<<NB, 256, 0, stream>>>(deg, part, N);
    scan_p2_k<<<1, 256, 0, stream>>>(part, NB, rowptr, N);
    scan_p3_k<<<NB, 256, 0, stream>>>(deg, part, rowptr, cursor, dinv, bcnt, N);
    bscanA_k<<<64, 256, 0, stream>>>(bcnt, bbase, tot, NB);
    perm_k<<<NB, 256, 0, stream>>>(deg, bbase, tot, perm, N);
    bucketB_k<<<8 * 64, T, 0, stream>>>(qtail, queue, cursor, csrc);

    // ---- conv0 linear (G-space output) ----
    mfma_lin_k<HID_C, IN_C, HID_C, true, true><<<LB, 256, 0, stream>>>(x, W0, dinv, bufA, MT);

    // ---- fused cooperative core: all 8 C=64 prop passes; result -> bufA ----
    int occ = 0;
    if (hipOccupancyMaxActiveBlocksPerMultiprocessor(&occ, prop_core_k, 256, 0)
            != hipSuccess || occ < 1) occ = 4;
    int G = cdiv(N, 32);               // 1563 full 1:1 coverage
    int cap = occ * 256;
    if (G > cap) G = cap;
    void* args[] = { &p, &G };
    hipLaunchCooperativeKernel((void*)prop_core_k, dim3(G), dim3(256), args, 0, stream);

    // ---- conv4: lin (padded 128 B out rows), 2 hops at 40ch, softmax ----
    mfma_lin_k<OUT_C, HID_C, HID_C, false, false><<<LB, 256, 0, stream>>>(
        bufA, W4, dinv, bufC, MT);
    prop40_k<<<P40B, T, 0, stream>>>(perm, rowptr, csrc, dinv, bufC, bufB, N);
    prop40_softmax_k<<<P40B, T, 0, stream>>>(perm, rowptr, csrc, dinv, bufB, b4, out, N);
}

// Round 5
// 318.483 us; speedup vs baseline: 7.7440x; 2.5797x over previous
//
#include <hip/hip_runtime.h>
#include <hip/hip_fp16.h>
#include <math.h>

#define N_NODES 50000
#define N_EDGES 800000
#define IN_C 96
#define HID_C 64
#define OUT_C 40
#define ALPHA 0.2f
#define NEG_SLOPE 0.01f
#define QCAP 131072  // per-partition queue capacity; mean 100k, ~100 sigma margin

typedef _Float16 f16x8 __attribute__((ext_vector_type(8)));
typedef float f32x4 __attribute__((ext_vector_type(4)));

__device__ __forceinline__ int edge_at(const void* ei, int is64, long long pos) {
    return is64 ? (int)((const long long*)ei)[pos] : ((const int*)ei)[pos];
}

// ---- zero deg + qtail + zero-row init + edge dtype detect (fused) ----
// Row N_NODES of each feature buffer is the shared ZERO ROW targeted by the
// alignment-pad entries in csrc; it is never written by any other kernel.
__global__ void zero_detect_k(int* deg, int n, int* qtail, const unsigned int* ei, int* flag,
                              __half* bufA, __half* bufB, __half* bufC) {
    int i = blockIdx.x * blockDim.x + threadIdx.x;
    if (i < n) deg[i] = 0;
    if (i < 8) qtail[i] = 0;
    if (i >= 8 && i < 32) {  // 24 threads: 3 bufs x 8 float4 = zero row N
        int j = i - 8;
        __half* b = (j < 8) ? bufA : (j < 16) ? bufB : bufC;
        ((float4*)b)[(size_t)N_NODES * 8 + (j & 7)] = make_float4(0.f, 0.f, 0.f, 0.f);
    }
    if (i == 0) {
        int is64 = 1;
        for (int j = 1; j < 16; j += 2)
            if (ei[j] != 0u) is64 = 0;
        *flag = is64;
    }
}

// ---- phase A: one pass over edges; block-level partition reservation ----
__global__ void bucketA_k(const void* ei, const int* flag, int* __restrict__ deg,
                          int* __restrict__ qtail, int2* __restrict__ queue, int E) {
    __shared__ int cnt[8], qb[8];
    int f = *flag;
    int e0 = blockIdx.x * 1024;
    if (threadIdx.x < 8) cnt[threadIdx.x] = 0;
    __syncthreads();
    int s[4], d[4], p[4], r[4];
    #pragma unroll
    for (int k = 0; k < 4; ++k) {
        int e = e0 + threadIdx.x + k * 256;
        if (e < E) {
            d[k] = edge_at(ei, f, (long long)E + e);
            s[k] = edge_at(ei, f, e);
            atomicAdd(&deg[d[k]], 1);
            p[k] = d[k] / (N_NODES / 8);
            if (p[k] > 7) p[k] = 7;
            r[k] = atomicAdd(&cnt[p[k]], 1);
        } else p[k] = -1;
    }
    __syncthreads();
    if (threadIdx.x < 8) qb[threadIdx.x] = atomicAdd(&qtail[threadIdx.x], cnt[threadIdx.x]);
    __syncthreads();
    #pragma unroll
    for (int k = 0; k < 4; ++k) {
        if (p[k] >= 0) {
            int pos = qb[p[k]] + r[k];
            if (pos < QCAP) queue[(size_t)p[k] * QCAP + pos] = make_int2(s[k], d[k]);
        }
    }
}

// ---- phase B: per-partition streaming scatter into csrc ----
__global__ void bucketB_k(const int* __restrict__ qtail, const int2* __restrict__ queue,
                          int* __restrict__ cursor, int* __restrict__ csrc) {
    int p = blockIdx.x & 7;
    int j = blockIdx.x >> 3;
    int J = gridDim.x >> 3;
    int n = qtail[p]; if (n > QCAP) n = QCAP;
    const int2* q = queue + (size_t)p * QCAP;
    for (int i = j * blockDim.x + threadIdx.x; i < n; i += J * blockDim.x) {
        int2 e = q[i];
        int pos = atomicAdd(&cursor[e.y], 1);
        csrc[pos] = e.x;
    }
}

// ---- parallel 3-phase exclusive scan over PADDED deg ((d+3)&~3) ----
__global__ void scan_p1_k(const int* __restrict__ deg, int* __restrict__ part, int n) {
    __shared__ int sm[256];
    int t = threadIdx.x, i = blockIdx.x * 256 + t;
    int v = (i < n) ? ((deg[i] + 3) & ~3) : 0;
    sm[t] = v;
    __syncthreads();
    for (int off = 1; off < 256; off <<= 1) {
        int u = (t >= off) ? sm[t - off] : 0;
        __syncthreads();
        sm[t] += u;
        __syncthreads();
    }
    if (t == 255) part[blockIdx.x] = sm[255];
}

__global__ void scan_p2_k(int* part, int nb, int* rowptr, int n) {
    __shared__ int sm[256];
    int t = threadIdx.x;
    int v = (t < nb) ? part[t] : 0;
    sm[t] = v;
    __syncthreads();
    for (int off = 1; off < 256; off <<= 1) {
        int u = (t >= off) ? sm[t - off] : 0;
        __syncthreads();
        sm[t] += u;
        __syncthreads();
    }
    if (t < nb) part[t] = sm[t] - v;  // exclusive
    if (t == 255) rowptr[n] = sm[255];
}

// scan_p3 + bucket histogram + pad-slot fill (pads -> zero-row index N)
__global__ void scan_p3_k(const int* __restrict__ deg, const int* __restrict__ part,
                          int* __restrict__ rowptr, int* __restrict__ cursor,
                          float* __restrict__ dinv, int* __restrict__ bcnt,
                          int* __restrict__ csrc, int n) {
    __shared__ int sm[256];
    __shared__ int h[64];
    int t = threadIdx.x, i = blockIdx.x * 256 + t;
    if (t < 64) h[t] = 0;
    int d = (i < n) ? deg[i] : 0;
    int v = (d + 3) & ~3;
    sm[t] = v;
    __syncthreads();
    for (int off = 1; off < 256; off <<= 1) {
        int u = (t >= off) ? sm[t - off] : 0;
        __syncthreads();
        sm[t] += u;
        __syncthreads();
    }
    if (i < n) {
        int excl = sm[t] - v + part[blockIdx.x];
        rowptr[i] = excl;
        cursor[i] = excl;
        dinv[i] = rsqrtf((float)d + 1.0f);  // +1 self loop
        for (int k = d; k < v; ++k) csrc[excl + k] = N_NODES;  // pad -> zero row
        int dd = d; if (dd > 63) dd = 63;
        atomicAdd(&h[63 - dd], 1);          // bucket = 63-deg (descending)
    }
    __syncthreads();
    if (t < 64) bcnt[blockIdx.x * 64 + t] = h[t];
}

__global__ void bscanA_k(const int* __restrict__ bcnt, int* __restrict__ bbase,
                         int* __restrict__ tot, int nb) {
    __shared__ int sm[256];
    int b = blockIdx.x;
    int t = threadIdx.x;
    int v = (t < nb) ? bcnt[t * 64 + b] : 0;
    sm[t] = v;
    __syncthreads();
    for (int off = 1; off < 256; off <<= 1) {
        int u = (t >= off) ? sm[t - off] : 0;
        __syncthreads();
        sm[t] += u;
        __syncthreads();
    }
    if (t < nb) bbase[t * 64 + b] = sm[t] - v;
    if (t == 255) tot[b] = sm[255];
}

__global__ void perm_k(const int* __restrict__ deg, const int* __restrict__ bbase,
                       const int* __restrict__ tot, int* __restrict__ perm, int n) {
    __shared__ int h[64], bs[64];
    int t = threadIdx.x, i = blockIdx.x * 256 + t;
    if (t < 64) { h[t] = 0; bs[t] = tot[t]; }
    __syncthreads();
    if (t == 0) {
        int run = 0;
        for (int k = 0; k < 64; ++k) { int v = bs[k]; bs[k] = run; run += v; }
    }
    __syncthreads();
    if (i < n) {
        int d = deg[i]; if (d > 63) d = 63;
        int b = 63 - d;
        int rank = atomicAdd(&h[b], 1);
        perm[bs[b] + bbase[blockIdx.x * 64 + b] + rank] = i;
    }
}

// ---------------- shared prop helpers ----------------
__device__ __forceinline__ void add8(float* acc, float4 v) {
    const __half2* hp = (const __half2*)&v;
    #pragma unroll
    for (int j = 0; j < 4; ++j) {
        float2 f = __half22float2(hp[j]);
        acc[2 * j] += f.x;
        acc[2 * j + 1] += f.y;
    }
}

__device__ __forceinline__ void unpack8(float* acc, float4 r) {
    const __half2* hp = (const __half2*)&r;
    #pragma unroll
    for (int j = 0; j < 4; ++j) {
        float2 f = __half22float2(hp[j]);
        acc[2 * j] = f.x;
        acc[2 * j + 1] = f.y;
    }
}

// 4-aligned gather: edge lists padded to multiples of 4 (pads hit the zero
// row), so the steady state is exactly ONE int4 index load + FOUR float4
// row-gathers per 4 edges — 1.25 VMEM instrs/edge vs 2.0 before. No tails.
__device__ __forceinline__ void gather4(const float4* __restrict__ in8, int ci,
        const int* __restrict__ csrc, int r0, int r1, float* acc) {
    if (r0 >= r1) return;
    int4 s = *(const int4*)(csrc + r0);
    int i = r0;
    for (; i + 4 < r1; i += 4) {
        float4 v0 = in8[(size_t)s.x * 8 + ci];
        float4 v1 = in8[(size_t)s.y * 8 + ci];
        float4 v2 = in8[(size_t)s.z * 8 + ci];
        float4 v3 = in8[(size_t)s.w * 8 + ci];
        s = *(const int4*)(csrc + i + 4);
        add8(acc, v0); add8(acc, v1); add8(acc, v2); add8(acc, v3);
    }
    {   // last batch
        float4 v0 = in8[(size_t)s.x * 8 + ci];
        float4 v1 = in8[(size_t)s.y * 8 + ci];
        float4 v2 = in8[(size_t)s.z * 8 + ci];
        float4 v3 = in8[(size_t)s.w * 8 + ci];
        add8(acc, v0); add8(acc, v1); add8(acc, v2); add8(acc, v3);
    }
}

// ---------------- C=64 prop: 8-lane group per NODE (degree-sorted) ------------
template <bool COMBINE, bool LEAKY, bool BIAS>
__global__ void __launch_bounds__(256) prop64_k(
        const int* __restrict__ perm,
        const int* __restrict__ rowptr, const int* __restrict__ csrc,
        const float* __restrict__ dinv,
        const __half* __restrict__ in, const __half* __restrict__ h0,
        const float* __restrict__ bias,
        __half* __restrict__ out, int N) {
    int g = blockIdx.x * (blockDim.x >> 3) + (threadIdx.x >> 3);
    int ci = threadIdx.x & 7;  // 8 lanes x 8ch = 64 channels
    if (g >= N) return;
    int node = perm[g];
    const float4* in8 = (const float4*)in;
    float acc[8];
    unpack8(acc, in8[(size_t)node * 8 + ci]);  // self-loop term G[node]
    int r0 = rowptr[node], r1 = rowptr[node + 1];
    gather4(in8, ci, csrc, r0, r1, acc);
    float di = dinv[node];
    float sc = di * di;
    float v[8];
    #pragma unroll
    for (int j = 0; j < 8; ++j) v[j] = sc * acc[j];
    if (BIAS) {
        float4 b0v = ((const float4*)bias)[2 * ci];
        float4 b1v = ((const float4*)bias)[2 * ci + 1];
        v[0] += di * b0v.x; v[1] += di * b0v.y; v[2] += di * b0v.z; v[3] += di * b0v.w;
        v[4] += di * b1v.x; v[5] += di * b1v.y; v[6] += di * b1v.z; v[7] += di * b1v.w;
    }
    if (COMBINE) {
        float h[8];
        unpack8(h, ((const float4*)h0)[(size_t)node * 8 + ci]);
        #pragma unroll
        for (int j = 0; j < 8; ++j) v[j] = (1.0f - ALPHA) * v[j] + ALPHA * h[j];
    }
    if (LEAKY) {
        #pragma unroll
        for (int j = 0; j < 8; ++j) v[j] = v[j] > 0.0f ? v[j] : NEG_SLOPE * v[j];
    }
    float4 o;
    __half2* op = (__half2*)&o;
    #pragma unroll
    for (int j = 0; j < 4; ++j)
        op[j] = __float22half2_rn(make_float2(v[2 * j], v[2 * j + 1]));
    ((float4*)out)[(size_t)node * 8 + ci] = o;
}

// ---------------- C=40 prop, padded 128 B rows ----------------
__global__ void __launch_bounds__(256) prop40_k(
        const int* __restrict__ perm,
        const int* __restrict__ rowptr, const int* __restrict__ csrc,
        const float* __restrict__ dinv,
        const __half* __restrict__ in, __half* __restrict__ out, int N) {
    int g = blockIdx.x * (blockDim.x >> 3) + (threadIdx.x >> 3);
    int ci = threadIdx.x & 7;
    if (g >= N) return;
    int node = perm[g];
    bool act = ci < 5;  // 5 lanes x 8ch = 40 channels
    int cc = act ? ci : 0;
    const float4* in4 = (const float4*)in;
    float acc[8];
    unpack8(acc, in4[(size_t)node * 8 + cc]);
    int r0 = rowptr[node], r1 = rowptr[node + 1];
    gather4(in4, cc, csrc, r0, r1, acc);
    if (act) {
        float di = dinv[node];
        float sc = di * di;
        float4 o;
        __half2* op = (__half2*)&o;
        #pragma unroll
        for (int j = 0; j < 4; ++j)
            op[j] = __float22half2_rn(make_float2(sc * acc[2 * j], sc * acc[2 * j + 1]));
        ((float4*)out)[(size_t)node * 8 + ci] = o;
    }
}

// ---------------- final C=40 prop + b4 + log_softmax, fp32 out ----------------
__global__ void __launch_bounds__(256) prop40_softmax_k(
        const int* __restrict__ perm,
        const int* __restrict__ rowptr, const int* __restrict__ csrc,
        const float* __restrict__ dinv,
        const __half* __restrict__ in, const float* __restrict__ bias,
        float* __restrict__ out, int N) {
    int g = blockIdx.x * (blockDim.x >> 3) + (threadIdx.x >> 3);
    int ci = threadIdx.x & 7;
    if (g >= N) return;
    int node = perm[g];
    bool act = ci < 5;
    int cc = act ? ci : 0;
    const float4* in4 = (const float4*)in;
    float acc[8];
    unpack8(acc, in4[(size_t)node * 8 + cc]);
    int r0 = rowptr[node], r1 = rowptr[node + 1];
    gather4(in4, cc, csrc, r0, r1, acc);
    float di = dinv[node];
    float v[8];
    if (act) {
        float4 b0v = ((const float4*)bias)[2 * ci];
        float4 b1v = ((const float4*)bias)[2 * ci + 1];
        v[0] = di * acc[0] + b0v.x; v[1] = di * acc[1] + b0v.y;
        v[2] = di * acc[2] + b0v.z; v[3] = di * acc[3] + b0v.w;
        v[4] = di * acc[4] + b1v.x; v[5] = di * acc[5] + b1v.y;
        v[6] = di * acc[6] + b1v.z; v[7] = di * acc[7] + b1v.w;
    } else {
        #pragma unroll
        for (int j = 0; j < 8; ++j) v[j] = -INFINITY;
    }
    float m = v[0];
    #pragma unroll
    for (int j = 1; j < 8; ++j) m = fmaxf(m, v[j]);
    #pragma unroll
    for (int off = 4; off >= 1; off >>= 1) m = fmaxf(m, __shfl_xor(m, off));
    float e = 0.0f;
    if (act) {
        #pragma unroll
        for (int j = 0; j < 8; ++j) e += expf(v[j] - m);
    }
    #pragma unroll
    for (int off = 4; off >= 1; off >>= 1) e += __shfl_xor(e, off);
    float ls = m + logf(e);
    if (act) {
        float4 o0 = make_float4(v[0] - ls, v[1] - ls, v[2] - ls, v[3] - ls);
        float4 o1 = make_float4(v[4] - ls, v[5] - ls, v[6] - ls, v[7] - ls);
        ((float4*)out)[(size_t)node * 10 + 2 * ci] = o0;
        ((float4*)out)[(size_t)node * 10 + 2 * ci + 1] = o1;
    }
}

// ---------------- MFMA dense linear ----------------
template <int O, int K, int OP, bool FP32IN, bool SCALE>
__global__ void __launch_bounds__(256) mfma_lin_k(const void* __restrict__ in_,
                                                  const float* __restrict__ W,
                                                  const float* __restrict__ dinv,
                                                  __half* __restrict__ out, int Mtiles) {
    constexpr int P2 = 52;
    __shared__ __half2 wsh[O * P2];
    for (int idx = threadIdx.x; idx < O * (K / 2); idx += 256) {
        int o = idx / (K / 2), kk = idx - o * (K / 2);
        float2 w2 = ((const float2*)W)[o * (K / 2) + kk];
        wsh[o * P2 + kk] = __floats2half2_rn(w2.x, w2.y);
    }
    __syncthreads();
    int wave = (blockIdx.x * 256 + threadIdx.x) >> 6;
    if (wave >= Mtiles) return;
    int lane = threadIdx.x & 63;
    int lm = lane & 15, q = lane >> 4;
    long long m0 = (long long)wave * 16;
    constexpr int NT = (O + 15) / 16;
    f32x4 acc[NT];
    #pragma unroll
    for (int j = 0; j < NT; ++j) acc[j] = (f32x4){0.f, 0.f, 0.f, 0.f};
    const __half* wsp = (const __half*)wsh;
    #pragma unroll
    for (int k0 = 0; k0 < K; k0 += 32) {
        f16x8 a;
        if (FP32IN) {
            const float* xr = (const float*)in_ + (m0 + lm) * K + k0 + q * 8;
            float4 x0 = ((const float4*)xr)[0];
            float4 x1 = ((const float4*)xr)[1];
            a = (f16x8){(_Float16)x0.x, (_Float16)x0.y, (_Float16)x0.z, (_Float16)x0.w,
                        (_Float16)x1.x, (_Float16)x1.y, (_Float16)x1.z, (_Float16)x1.w};
        } else {
            const __half* xr = (const __half*)in_ + (m0 + lm) * K + k0 + q * 8;
            a = *(const f16x8*)xr;
        }
        #pragma unroll
        for (int j = 0; j < NT; ++j) {
            f16x8 b = *(const f16x8*)(wsp + (16 * j + lm) * (2 * P2) + k0 + q * 8);
            acc[j] = __builtin_amdgcn_mfma_f32_16x16x32_f16(a, b, acc[j], 0, 0, 0);
        }
    }
    #pragma unroll
    for (int r = 0; r < 4; ++r) {
        long long m = m0 + q * 4 + r;
        float sc = SCALE ? dinv[m] : 1.0f;
        #pragma unroll
        for (int j = 0; j < NT; ++j) {
            int col = 16 * j + lm;
            if (col < O) out[m * OP + col] = __float2half(acc[j][r] * sc);
        }
    }
}

// ---------------- launcher ----------------
static inline int cdiv(long long a, long long b) { return (int)((a + b - 1) / b); }
static inline size_t align256(size_t x) { return (x + 255) & ~(size_t)255; }

extern "C" void kernel_launch(void* const* d_in, const int* in_sizes, int n_in,
                              void* d_out, int out_size, void* d_ws, size_t ws_size,
                              hipStream_t stream) {
    const float* x  = (const float*)d_in[0];
    const void*  ei = d_in[1];
    const float* W0 = (const float*)d_in[2];
    const float* b0 = (const float*)d_in[3];
    const float* W4 = (const float*)d_in[4];
    const float* b4 = (const float*)d_in[5];
    float* out = (float*)d_out;

    const int N = N_NODES, E = N_EDGES;
    const int NB = cdiv(N, 256);  // 196
    const int EP = E + 4 * N;     // padded csrc capacity
    char* ws = (char*)d_ws;
    int*    flag   = (int*)ws;     ws += 256;
    int*    deg    = (int*)ws;     ws += align256((size_t)N * 4);
    int*    rowptr = (int*)ws;     ws += align256((size_t)(N + 1) * 4);
    int*    cursor = (int*)ws;     ws += align256((size_t)N * 4);
    int*    part   = (int*)ws;     ws += align256(256 * 4);
    int*    bcnt   = (int*)ws;     ws += align256((size_t)NB * 64 * 4);
    int*    bbase  = (int*)ws;     ws += align256((size_t)NB * 64 * 4);
    int*    tot    = (int*)ws;     ws += align256(64 * 4);
    int*    qtail  = (int*)ws;     ws += align256(8 * 4);
    int*    perm   = (int*)ws;     ws += align256((size_t)N * 4);
    float*  dinv   = (float*)ws;   ws += align256((size_t)N * 4);
    int*    csrc   = (int*)ws;     ws += align256((size_t)EP * 4);
    int2*   queue  = (int2*)ws;    ws += align256((size_t)8 * QCAP * 8);
    __half* bufA   = (__half*)ws;  ws += align256((size_t)(N + 1) * HID_C * 2);
    __half* bufB   = (__half*)ws;  ws += align256((size_t)(N + 1) * HID_C * 2);
    __half* bufC   = (__half*)ws;  ws += align256((size_t)(N + 1) * HID_C * 2);

    const int T = 256;
    const int MT = N / 16;             // 3125 MFMA tiles
    const int LB = cdiv(MT, 4);        // mfma_lin blocks (4 waves each)
    const int P64B = cdiv(N, T / 8);   // prop blocks (32 groups each)

    // ---- CSR build (padded-to-4 rows; pads -> zero row N) + degree sort ----
    zero_detect_k<<<cdiv(N, T), T, 0, stream>>>(deg, N, qtail, (const unsigned int*)ei, flag,
                                                bufA, bufB, bufC);
    bucketA_k<<<cdiv(E, 1024), T, 0, stream>>>(ei, flag, deg, qtail, queue, E);
    scan_p1_k<<<NB, 256, 0, stream>>>(deg, part, N);
    scan_p2_k<<<1, 256, 0, stream>>>(part, NB, rowptr, N);
    scan_p3_k<<<NB, 256, 0, stream>>>(deg, part, rowptr, cursor, dinv, bcnt, csrc, N);
    bscanA_k<<<64, 256, 0, stream>>>(bcnt, bbase, tot, NB);
    perm_k<<<NB, 256, 0, stream>>>(deg, bbase, tot, perm, N);
    bucketB_k<<<8 * 64, T, 0, stream>>>(qtail, queue, cursor, csrc);

    // ---- conv0 (SGConv, K=2): linear folded first; output G-space ----
    mfma_lin_k<HID_C, IN_C, HID_C, true, true><<<LB, 256, 0, stream>>>(x, W0, dinv, bufA, MT);
    prop64_k<false, false, false><<<P64B, T, 0, stream>>>(
        perm, rowptr, csrc, dinv, bufA, nullptr, nullptr, bufB, N);
    prop64_k<false, false, true><<<P64B, T, 0, stream>>>(
        perm, rowptr, csrc, dinv, bufB, nullptr, b0, bufC, N);  // + dinv*b0 -> Gh0

    // ---- conv1..conv3: leaky(APPNP(h)) entirely in G-space, Gh0 = bufC ----
    for (int r = 0; r < 3; ++r) {
        prop64_k<true, false, false><<<P64B, T, 0, stream>>>(
            perm, rowptr, csrc, dinv, bufC, bufC, nullptr, bufB, N);
        // in-place bufC write safe: Gh0[node] read only by the group writing it
        prop64_k<true, true, false><<<P64B, T, 0, stream>>>(
            perm, rowptr, csrc, dinv, bufB, bufC, nullptr, bufC, N);
    }

    // ---- conv4 (SGConv, K=2): G-space lin, then 2 hops at 40ch ----
    mfma_lin_k<OUT_C, HID_C, HID_C, false, false><<<LB, 256, 0, stream>>>(
        bufC, W4, dinv, bufA, MT);
    prop40_k<<<P64B, T, 0, stream>>>(perm, rowptr, csrc, dinv, bufA, bufB, N);
    prop40_softmax_k<<<P64B, T, 0, stream>>>(perm, rowptr, csrc, dinv, bufB, b4, out, N);
}